// Round 19
// baseline (62.276 us; speedup 1.0000x reference)
//
#include <hip/hip_runtime.h>

#define NROWS 8192
#define NCOLS 4096
#define LAMB  0.1
#define NBUCK 8192

typedef unsigned int u32;
typedef unsigned long long u64;

// ---------------------------------------------------------------------------
// Kernel 1: per-row squared error sum. ONE 256-THREAD BLOCK PER ROW.
// Byte-identical to R10/R13/R18 (best measured; ~41 us in-bench, warm L3).
// ---------------------------------------------------------------------------
__global__ __launch_bounds__(256) void rowerr_kernel(const float* __restrict__ inp,
                                                     const float* __restrict__ tgt,
                                                     float* __restrict__ err) {
    const int row = blockIdx.x;
    const float4* a = reinterpret_cast<const float4*>(inp + (size_t)row * NCOLS);
    const float4* b = reinterpret_cast<const float4*>(tgt + (size_t)row * NCOLS);
    const int t = threadIdx.x;

    float acc = 0.f;
#pragma unroll
    for (int c = 0; c < 4; ++c) {
        float4 va = a[t + c * 256];
        float4 vb = b[t + c * 256];
        float dx = va.x - vb.x;
        float dy = va.y - vb.y;
        float dz = va.z - vb.z;
        float dw = va.w - vb.w;
        acc += dx * dx + dy * dy + dz * dz + dw * dw;
    }

#pragma unroll
    for (int off = 32; off > 0; off >>= 1) acc += __shfl_down(acc, off, 64);

    __shared__ float ws[4];
    const int lane = t & 63, wv = t >> 6;
    if (lane == 0) ws[wv] = acc;
    __syncthreads();
    if (t == 0) err[row] = ws[0] + ws[1] + ws[2] + ws[3];
}

// ---------------------------------------------------------------------------
// fast f64 reciprocal: f32 seed + 2 Newton steps (~1 ulp, no f64 divide)
// ---------------------------------------------------------------------------
__device__ __forceinline__ double fastrcp(double x) {
    double r = (double)(1.0f / (float)x);
    r = r * (2.0 - x * r);
    r = r * (2.0 - x * r);
    return r;
}

// ---------------------------------------------------------------------------
// Kernel 2: single block, 1024 threads. Bucket sort + exact rank, v4:
//   8192 buckets (shift = nbits-13). The err distribution is a concentrated
//   bell in float-bit space; 4096 linear buckets left central buckets with
//   ~9-18 elems (hot-bucket atomic serialization + long rank loops). 8192
//   buckets halve central occupancy to ~4-5. LDS ~96 KB (single block, OK).
//   - ONE atomic round: atomicAdd return = in-bucket arrival seq (myq);
//     scatter is a plain LDS write to base2[bk]+myq.
//   - exact in-bucket rank (reads only) -> barrier -> in-place write
//   - obj: f64 scan of cs, total of cs2, argmax of
//     h(k) = cs^2/k + (total-cs)^2/(n-k)   (== argmin (Sw1+Sw2)/Sb)
// Exact permutation for any input (degenerate = slower, still exact).
// ---------------------------------------------------------------------------
__global__ __launch_bounds__(1024) void drae_kernel(const float* __restrict__ err,
                                                    float* __restrict__ out) {
    const int N = NROWS;
    __shared__ u32 bufB[NROWS];            // 32 KB  scattered -> sorted (in place)
    __shared__ u32 hist[NBUCK];            // 32 KB  counts (never overwritten)
    __shared__ u32 base2[NBUCK];           // 32 KB  segment starts
    __shared__ u32 sMin[16], sMax[16], saux[16];
    __shared__ double auxX[16], auxT2[16], redH[16], redCs[16];
    __shared__ int    redIdx[16];

    const int tid  = threadIdx.x;
    const int lane = tid & 63, wv = tid >> 6;

    // ---- stage err as float4 -> regs; min/max; zero hist ----
    u32 bits[8];
    {
        const float4* e4 = reinterpret_cast<const float4*>(err);
        const float4 f0 = e4[tid];
        const float4 f1 = e4[tid + 1024];
        bits[0] = __float_as_uint(f0.x);
        bits[1] = __float_as_uint(f0.y);
        bits[2] = __float_as_uint(f0.z);
        bits[3] = __float_as_uint(f0.w);
        bits[4] = __float_as_uint(f1.x);
        bits[5] = __float_as_uint(f1.y);
        bits[6] = __float_as_uint(f1.z);
        bits[7] = __float_as_uint(f1.w);
    }
    u32 mn = 0xFFFFFFFFu, mx = 0u;
#pragma unroll
    for (int k = 0; k < 8; ++k) { mn = min(mn, bits[k]); mx = max(mx, bits[k]); }
#pragma unroll
    for (int off = 32; off > 0; off >>= 1) {
        mn = min(mn, (u32)__shfl_xor((int)mn, off, 64));
        mx = max(mx, (u32)__shfl_xor((int)mx, off, 64));
    }
    if (lane == 0) { sMin[wv] = mn; sMax[wv] = mx; }

#pragma unroll
    for (int k = 0; k < 8; ++k) hist[tid + k * 1024] = 0;
    __syncthreads();

    u32 minb = sMin[0], maxb = sMax[0];
#pragma unroll
    for (int w = 1; w < 16; ++w) { minb = min(minb, sMin[w]); maxb = max(maxb, sMax[w]); }
    const u32 range = maxb - minb;
    const int nbits = 32 - __clz(range | 1u);          // >= 1
    const int shift = (nbits > 13) ? (nbits - 13) : 0; // bucket < 8192

    // ---- single atomic round: count AND capture in-bucket sequence ----
    u32 bk[8], myq[8];
#pragma unroll
    for (int k = 0; k < 8; ++k) {
        bits[k] -= minb;
        bk[k] = bits[k] >> shift;
        myq[k] = atomicAdd(&hist[bk[k]], 1u);          // return = my seq in bucket
    }
    __syncthreads();

    // ---- exclusive scan of 8192 counts (8 per thread); hist stays counts ----
    u32 c[8];
    u32 tsum = 0;
#pragma unroll
    for (int k = 0; k < 8; ++k) { c[k] = hist[8 * tid + k]; tsum += c[k]; }
    u32 incl = tsum;
#pragma unroll
    for (int off = 1; off < 64; off <<= 1) {
        const u32 t = __shfl_up(incl, off, 64);
        if (lane >= off) incl += t;
    }
    if (lane == 63) saux[wv] = incl;
    __syncthreads();
    u32 add = 0;
#pragma unroll
    for (int w = 0; w < 16; ++w) if (w < wv) add += saux[w];
    u32 run = add + incl - tsum;
#pragma unroll
    for (int k = 0; k < 8; ++k) { base2[8 * tid + k] = run; run += c[k]; }
    __syncthreads();

    // ---- plain-write scatter (no atomics: slot = base + seq) ----
#pragma unroll
    for (int k = 0; k < 8; ++k) bufB[base2[bk[k]] + myq[k]] = bits[k];
    __syncthreads();

    // ---- exact rank within bucket (reads only) ----
    u32 pos[8];
#pragma unroll
    for (int k = 0; k < 8; ++k) {
        const u32 s = base2[bk[k]];
        const u32 cc = hist[bk[k]];
        const u32 ki = bits[k];
        u32 r = 0;
        for (u32 q = 0; q < cc; ++q) {
            const u32 v = bufB[s + q];
            r += (v < ki || (v == ki && q < myq[k])) ? 1u : 0u;
        }
        pos[k] = s + r;
    }
    __syncthreads();                       // all rank reads complete

    // ---- in-place sorted write ----
#pragma unroll
    for (int k = 0; k < 8; ++k) bufB[pos[k]] = bits[k];
    __syncthreads();                       // bufB fully sorted (biased keys)

    // ================= obj phase ==========================================
    float v[8];
#pragma unroll
    for (int r = 0; r < 8; ++r) v[r] = __uint_as_float(bufB[(tid << 3) + r] + minb);

    double sx = 0.0, sx2 = 0.0;
#pragma unroll
    for (int r = 0; r < 8; ++r) {
        sx  += (double)v[r];
        sx2 += (double)v[r] * (double)v[r];
    }

    // wave inclusive scan of sx; wave total of sx2
    double ix = sx;
#pragma unroll
    for (int off = 1; off < 64; off <<= 1) {
        double t1 = __shfl_up(ix, off, 64);
        if (lane >= off) ix += t1;
    }
    double t2 = sx2;
#pragma unroll
    for (int off = 32; off > 0; off >>= 1) t2 += __shfl_xor(t2, off, 64);

    if (lane == 63) auxX[wv]  = ix;
    if (lane == 0)  auxT2[wv] = t2;
    __syncthreads();

    double wOff1 = 0.0, total1 = 0.0, total2 = 0.0;
#pragma unroll
    for (int w = 0; w < 16; ++w) {
        const double a1 = auxX[w];
        if (w < wv) wOff1 += a1;
        total1 += a1;
        total2 += auxT2[w];
    }
    const double exc1 = wOff1 + (ix - sx);
    const double nf = (double)N;

    // on-the-fly h(k) + local argmax (== argmin obj), first index on ties
    double run1 = exc1;
    double bestH = -1e300, bestCs = 0.0;
    int bestIdx = N;
#pragma unroll
    for (int r = 0; r < 8; ++r) {
        const int idx = (tid << 3) + r;
        run1 += (double)v[r];
        if (idx < N - 1) {
            const double kf  = (double)(idx + 1);
            const double rem = total1 - run1;
            const double h   = run1 * run1 * fastrcp(kf) +
                               rem  * rem  * fastrcp(nf - kf);
            if (h > bestH) { bestH = h; bestIdx = idx; bestCs = run1; }
        }
    }

    // wave argmax reduce (max h, first index on ties)
#pragma unroll
    for (int off = 32; off > 0; off >>= 1) {
        const double oH   = __shfl_down(bestH, off, 64);
        const int    oIdx = __shfl_down(bestIdx, off, 64);
        const double oCs  = __shfl_down(bestCs, off, 64);
        if (oH > bestH || (oH == bestH && oIdx < bestIdx)) {
            bestH = oH; bestIdx = oIdx; bestCs = oCs;
        }
    }
    if (lane == 0) { redH[wv] = bestH; redIdx[wv] = bestIdx; redCs[wv] = bestCs; }
    __syncthreads();

    if (tid == 0) {
        double bH = redH[0], bCs = redCs[0];
        int bIdx = redIdx[0];
        for (int w = 1; w < 16; ++w) {
            if (redH[w] > bH || (redH[w] == bH && redIdx[w] < bIdx)) {
                bH = redH[w]; bIdx = redIdx[w]; bCs = redCs[w];
            }
        }
        const double Sb     = total2 - total1 * total1 / nf;
        const double optObj = (total2 - bH) / Sb;
        const double T      = (double)(bIdx + 1);
        out[0] = (float)(bCs / T + LAMB * optObj);
    }
}

// ---------------------------------------------------------------------------
extern "C" void kernel_launch(void* const* d_in, const int* in_sizes, int n_in,
                              void* d_out, int out_size, void* d_ws, size_t ws_size,
                              hipStream_t stream) {
    const float* inp = (const float*)d_in[0];
    const float* tgt = (const float*)d_in[1];
    float* errbuf = (float*)d_ws;   // 8192 f32 = 32 KB scratch

    rowerr_kernel<<<NROWS, 256, 0, stream>>>(inp, tgt, errbuf);
    drae_kernel<<<1, 1024, 0, stream>>>(errbuf, (float*)d_out);
}

// Round 20
// 61.862 us; speedup vs baseline: 1.0067x; 1.0067x over previous
//
#include <hip/hip_runtime.h>

#define NROWS 8192
#define NCOLS 4096
#define LAMB  0.1
#define NBUCK 4096

typedef unsigned int u32;
typedef unsigned long long u64;

// ---------------------------------------------------------------------------
// Kernel 1: per-row squared error sum. ONE 256-THREAD BLOCK PER ROW.
// Byte-identical to R10/R13/R18. In-bench ~42 us = 6.4 TB/s aggregate read
// (~101% of achievable HBM ceiling; L3 serves ~half) -- at the roofline.
// ---------------------------------------------------------------------------
__global__ __launch_bounds__(256) void rowerr_kernel(const float* __restrict__ inp,
                                                     const float* __restrict__ tgt,
                                                     float* __restrict__ err) {
    const int row = blockIdx.x;
    const float4* a = reinterpret_cast<const float4*>(inp + (size_t)row * NCOLS);
    const float4* b = reinterpret_cast<const float4*>(tgt + (size_t)row * NCOLS);
    const int t = threadIdx.x;

    float acc = 0.f;
#pragma unroll
    for (int c = 0; c < 4; ++c) {
        float4 va = a[t + c * 256];
        float4 vb = b[t + c * 256];
        float dx = va.x - vb.x;
        float dy = va.y - vb.y;
        float dz = va.z - vb.z;
        float dw = va.w - vb.w;
        acc += dx * dx + dy * dy + dz * dz + dw * dw;
    }

#pragma unroll
    for (int off = 32; off > 0; off >>= 1) acc += __shfl_down(acc, off, 64);

    __shared__ float ws[4];
    const int lane = t & 63, wv = t >> 6;
    if (lane == 0) ws[wv] = acc;
    __syncthreads();
    if (t == 0) err[row] = ws[0] + ws[1] + ws[2] + ws[3];
}

// ---------------------------------------------------------------------------
// fast f64 reciprocal: f32 seed + 2 Newton steps (~1 ulp, no f64 divide)
// ---------------------------------------------------------------------------
__device__ __forceinline__ double fastrcp(double x) {
    double r = (double)(1.0f / (float)x);
    r = r * (2.0 - x * r);
    r = r * (2.0 - x * r);
    return r;
}

// ---------------------------------------------------------------------------
// Kernel 2: single block, 1024 threads. Bucket sort + exact rank, v5 =
// best-of-all-rounds combo:
//   - 4096 buckets (R18's best; R19's 8192 was null)
//   - ONE atomic round: atomicAdd return = in-bucket arrival seq (myq);
//     scatter is a plain LDS write to base2[bk]+myq          (R18)
//   - SEPARATE output buffer bufS: rank-read of bufB and sorted-write to
//     bufS share one phase -> one fewer barrier, no in-place round-trip (R13)
//   1. float4-stage err -> regs; min/max via shuffle; zero hist
//   2. single LDS-atomic histogram round
//   3. exclusive scan of 4096 counts (4/thread); hist stays = counts
//   4. plain-write scatter to bufB[base2[bk]+myq]
//   5. exact in-bucket rank (reads bufB) + write bufS[s+r] in SAME phase
//   6. obj: f64 scan of cs, total of cs2, argmax of
//      h(k) = cs^2/k + (total-cs)^2/(n-k)   (== argmin (Sw1+Sw2)/Sb)
// LDS ~96 KB (single resident block -- fine). Exact for any input.
// ---------------------------------------------------------------------------
__global__ __launch_bounds__(1024) void drae_kernel(const float* __restrict__ err,
                                                    float* __restrict__ out) {
    const int N = NROWS;
    __shared__ u32 bufB[NROWS];            // 32 KB  bucket-grouped (arrival order)
    __shared__ u32 bufS[NROWS];            // 32 KB  fully sorted
    __shared__ u32 hist[NBUCK];            // 16 KB  counts (never overwritten)
    __shared__ u32 base2[NBUCK];           // 16 KB  segment starts
    __shared__ u32 sMin[16], sMax[16], saux[16];
    __shared__ double auxX[16], auxT2[16], redH[16], redCs[16];
    __shared__ int    redIdx[16];

    const int tid  = threadIdx.x;
    const int lane = tid & 63, wv = tid >> 6;

    // ---- stage err as float4 -> regs; min/max; zero hist ----
    u32 bits[8];
    {
        const float4* e4 = reinterpret_cast<const float4*>(err);
        const float4 f0 = e4[tid];
        const float4 f1 = e4[tid + 1024];
        bits[0] = __float_as_uint(f0.x);
        bits[1] = __float_as_uint(f0.y);
        bits[2] = __float_as_uint(f0.z);
        bits[3] = __float_as_uint(f0.w);
        bits[4] = __float_as_uint(f1.x);
        bits[5] = __float_as_uint(f1.y);
        bits[6] = __float_as_uint(f1.z);
        bits[7] = __float_as_uint(f1.w);
    }
    u32 mn = 0xFFFFFFFFu, mx = 0u;
#pragma unroll
    for (int k = 0; k < 8; ++k) { mn = min(mn, bits[k]); mx = max(mx, bits[k]); }
#pragma unroll
    for (int off = 32; off > 0; off >>= 1) {
        mn = min(mn, (u32)__shfl_xor((int)mn, off, 64));
        mx = max(mx, (u32)__shfl_xor((int)mx, off, 64));
    }
    if (lane == 0) { sMin[wv] = mn; sMax[wv] = mx; }

#pragma unroll
    for (int k = 0; k < 4; ++k) hist[tid + k * 1024] = 0;
    __syncthreads();                                   // B1

    u32 minb = sMin[0], maxb = sMax[0];
#pragma unroll
    for (int w = 1; w < 16; ++w) { minb = min(minb, sMin[w]); maxb = max(maxb, sMax[w]); }
    const u32 range = maxb - minb;
    const int nbits = 32 - __clz(range | 1u);          // >= 1
    const int shift = (nbits > 12) ? (nbits - 12) : 0; // bucket < 4096

    // ---- single atomic round: count AND capture in-bucket sequence ----
    u32 bk[8], myq[8];
#pragma unroll
    for (int k = 0; k < 8; ++k) {
        bits[k] -= minb;
        bk[k] = bits[k] >> shift;
        myq[k] = atomicAdd(&hist[bk[k]], 1u);          // return = my seq in bucket
    }
    __syncthreads();                                   // B2

    // ---- exclusive scan of 4096 counts (4 per thread); hist stays counts ----
    const u32 c0 = hist[4 * tid],     c1 = hist[4 * tid + 1];
    const u32 c2 = hist[4 * tid + 2], c3 = hist[4 * tid + 3];
    const u32 tsum = (c0 + c1) + (c2 + c3);
    u32 incl = tsum;
#pragma unroll
    for (int off = 1; off < 64; off <<= 1) {
        const u32 t = __shfl_up(incl, off, 64);
        if (lane >= off) incl += t;
    }
    if (lane == 63) saux[wv] = incl;
    __syncthreads();                                   // B3
    u32 add = 0;
#pragma unroll
    for (int w = 0; w < 16; ++w) if (w < wv) add += saux[w];
    const u32 excl = add + incl - tsum;
    base2[4 * tid]     = excl;
    base2[4 * tid + 1] = excl + c0;
    base2[4 * tid + 2] = excl + c0 + c1;
    base2[4 * tid + 3] = excl + c0 + c1 + c2;
    __syncthreads();                                   // B4

    // ---- plain-write scatter (no atomics: slot = base + seq) ----
#pragma unroll
    for (int k = 0; k < 8; ++k) bufB[base2[bk[k]] + myq[k]] = bits[k];
    __syncthreads();                                   // B5

    // ---- exact rank (reads bufB) + sorted write (bufS) in one phase ----
#pragma unroll
    for (int k = 0; k < 8; ++k) {
        const u32 s = base2[bk[k]];
        const u32 c = hist[bk[k]];
        const u32 ki = bits[k];
        u32 r = 0;
        for (u32 q = 0; q < c; ++q) {
            const u32 v = bufB[s + q];
            r += (v < ki || (v == ki && q < myq[k])) ? 1u : 0u;
        }
        bufS[s + r] = ki;
    }
    __syncthreads();                                   // B6: bufS sorted

    // ================= obj phase ==========================================
    float v[8];
#pragma unroll
    for (int r = 0; r < 8; ++r) v[r] = __uint_as_float(bufS[(tid << 3) + r] + minb);

    double sx = 0.0, sx2 = 0.0;
#pragma unroll
    for (int r = 0; r < 8; ++r) {
        sx  += (double)v[r];
        sx2 += (double)v[r] * (double)v[r];
    }

    // wave inclusive scan of sx; wave total of sx2
    double ix = sx;
#pragma unroll
    for (int off = 1; off < 64; off <<= 1) {
        double t1 = __shfl_up(ix, off, 64);
        if (lane >= off) ix += t1;
    }
    double t2 = sx2;
#pragma unroll
    for (int off = 32; off > 0; off >>= 1) t2 += __shfl_xor(t2, off, 64);

    if (lane == 63) auxX[wv]  = ix;
    if (lane == 0)  auxT2[wv] = t2;
    __syncthreads();                                   // B7

    double wOff1 = 0.0, total1 = 0.0, total2 = 0.0;
#pragma unroll
    for (int w = 0; w < 16; ++w) {
        const double a1 = auxX[w];
        if (w < wv) wOff1 += a1;
        total1 += a1;
        total2 += auxT2[w];
    }
    const double exc1 = wOff1 + (ix - sx);
    const double nf = (double)N;

    // on-the-fly h(k) + local argmax (== argmin obj), first index on ties
    double run1 = exc1;
    double bestH = -1e300, bestCs = 0.0;
    int bestIdx = N;
#pragma unroll
    for (int r = 0; r < 8; ++r) {
        const int idx = (tid << 3) + r;
        run1 += (double)v[r];
        if (idx < N - 1) {
            const double kf  = (double)(idx + 1);
            const double rem = total1 - run1;
            const double h   = run1 * run1 * fastrcp(kf) +
                               rem  * rem  * fastrcp(nf - kf);
            if (h > bestH) { bestH = h; bestIdx = idx; bestCs = run1; }
        }
    }

    // wave argmax reduce (max h, first index on ties)
#pragma unroll
    for (int off = 32; off > 0; off >>= 1) {
        const double oH   = __shfl_down(bestH, off, 64);
        const int    oIdx = __shfl_down(bestIdx, off, 64);
        const double oCs  = __shfl_down(bestCs, off, 64);
        if (oH > bestH || (oH == bestH && oIdx < bestIdx)) {
            bestH = oH; bestIdx = oIdx; bestCs = oCs;
        }
    }
    if (lane == 0) { redH[wv] = bestH; redIdx[wv] = bestIdx; redCs[wv] = bestCs; }
    __syncthreads();                                   // B8

    if (tid == 0) {
        double bH = redH[0], bCs = redCs[0];
        int bIdx = redIdx[0];
        for (int w = 1; w < 16; ++w) {
            if (redH[w] > bH || (redH[w] == bH && redIdx[w] < bIdx)) {
                bH = redH[w]; bIdx = redIdx[w]; bCs = redCs[w];
            }
        }
        const double Sb     = total2 - total1 * total1 / nf;
        const double optObj = (total2 - bH) / Sb;
        const double T      = (double)(bIdx + 1);
        out[0] = (float)(bCs / T + LAMB * optObj);
    }
}

// ---------------------------------------------------------------------------
extern "C" void kernel_launch(void* const* d_in, const int* in_sizes, int n_in,
                              void* d_out, int out_size, void* d_ws, size_t ws_size,
                              hipStream_t stream) {
    const float* inp = (const float*)d_in[0];
    const float* tgt = (const float*)d_in[1];
    float* errbuf = (float*)d_ws;   // 8192 f32 = 32 KB scratch

    rowerr_kernel<<<NROWS, 256, 0, stream>>>(inp, tgt, errbuf);
    drae_kernel<<<1, 1024, 0, stream>>>(errbuf, (float*)d_out);
}